// Round 7
// baseline (238.982 us; speedup 1.0000x reference)
//
#include <hip/hip_runtime.h>
#include <stdint.h>

#define B_ 4096
#define T_ 49
#define H_ 512
#define BT_ (B_*T_)
#define BB 16

typedef __bf16 bf16x8 __attribute__((ext_vector_type(8)));
typedef float  f32x4  __attribute__((ext_vector_type(4)));
typedef unsigned short ushort_;

__device__ __forceinline__ ushort_ f2bf(float f){
  unsigned int u = __float_as_uint(f);
  u += 0x7fffu + ((u >> 16) & 1u);           // RNE
  return (ushort_)(u >> 16);
}

__device__ __forceinline__ float fast_tanh(float x){
  float e = __expf(2.0f * x);
  return 1.0f - 2.0f * __builtin_amdgcn_rcpf(e + 1.0f);
}

// k_pack: W [K][N] f32 -> fragment-ordered bf16.
__global__ __launch_bounds__(256) void k_pack(const float* __restrict__ W,
                                              ushort_* __restrict__ pack){
  int idx = blockIdx.x * 256 + threadIdx.x;   // 0..32767
  int lane = idx & 63;
  int gt   = (idx >> 6) & 31;
  int kk   = idx >> 11;
  int col  = gt*16 + (lane & 15);
  int k0   = kk*32 + (lane >> 4)*8;
  ushort4 lo, hi;
  lo.x = f2bf(W[(k0+0)*H_ + col]);
  lo.y = f2bf(W[(k0+1)*H_ + col]);
  lo.z = f2bf(W[(k0+2)*H_ + col]);
  lo.w = f2bf(W[(k0+3)*H_ + col]);
  hi.x = f2bf(W[(k0+4)*H_ + col]);
  hi.y = f2bf(W[(k0+5)*H_ + col]);
  hi.z = f2bf(W[(k0+6)*H_ + col]);
  hi.w = f2bf(W[(k0+7)*H_ + col]);
  ushort4* dst = (ushort4*)pack;
  dst[idx*2]   = lo;
  dst[idx*2+1] = hi;
}

// k_proj2 (MFMA): 16 batches/block; h@W_h and s@W_s; epilogue hpb & beta.
__global__ __launch_bounds__(256) void k_proj2(
    const float* __restrict__ h, const float* __restrict__ s,
    const ushort_* __restrict__ whp, const ushort_* __restrict__ wsp,
    const float* __restrict__ bh, const float* __restrict__ bs,
    const float* __restrict__ bv, const float* __restrict__ wbeta,
    const float* __restrict__ bbeta_p,
    float* __restrict__ hpb, float* __restrict__ beta)
{
  __shared__ __align__(16) ushort_ hl[16*H_];   // 16KB, A-frag order
  __shared__ __align__(16) ushort_ sl[16*H_];
  __shared__ float zwp[4][16];
  const int tid = threadIdx.x;
  const int w = tid >> 6, lane = tid & 63;
  const int l15 = lane & 15, l4 = lane >> 4;
  const int b0 = blockIdx.x * 16;

  {
    const int r = tid >> 4;
    const float4* hsrc = (const float4*)(h + (size_t)(b0+r)*H_);
    const float4* ssrc = (const float4*)(s + (size_t)(b0+r)*H_);
    #pragma unroll
    for(int p=0;p<8;p++){
      int q  = (tid & 15) + p*16;         // float4 col
      int k0 = q*4;
      float4 fh = hsrc[q];
      float4 fs = ssrc[q];
      int idx = (k0>>5)*512 + ((((k0&31)>>3)<<4) + r)*8 + (k0&7);
      ushort4 uh; uh.x=f2bf(fh.x); uh.y=f2bf(fh.y); uh.z=f2bf(fh.z); uh.w=f2bf(fh.w);
      ushort4 us; us.x=f2bf(fs.x); us.y=f2bf(fs.y); us.z=f2bf(fs.z); us.w=f2bf(fs.w);
      *(ushort4*)&hl[idx] = uh;
      *(ushort4*)&sl[idx] = us;
    }
  }
  __syncthreads();

  const bf16x8* __restrict__ bph = (const bf16x8*)whp;
  const bf16x8* __restrict__ bps = (const bf16x8*)wsp;
  const int bbase = w*512 + lane;

  f32x4 acch[8], accs[8];
  #pragma unroll
  for(int ni=0;ni<8;ni++){ acch[ni]=(f32x4){0,0,0,0}; accs[ni]=(f32x4){0,0,0,0}; }

  #pragma unroll 2
  for(int kk=0;kk<16;kk++){
    bf16x8 ah = *(const bf16x8*)&hl[kk*512 + lane*8];
    bf16x8 as2 = *(const bf16x8*)&sl[kk*512 + lane*8];
    #pragma unroll
    for(int ni=0;ni<8;ni++){
      acch[ni] = __builtin_amdgcn_mfma_f32_16x16x32_bf16(ah,  bph[kk*2048 + bbase + ni*64], acch[ni], 0,0,0);
      accs[ni] = __builtin_amdgcn_mfma_f32_16x16x32_bf16(as2, bps[kk*2048 + bbase + ni*64], accs[ni], 0,0,0);
    }
  }

  float bhv[8], bsv[8], bvv[8], wbv[8];
  #pragma unroll
  for(int ni=0;ni<8;ni++){
    int col = w*128 + ni*16 + l15;
    bhv[ni] = bh[col]; bsv[ni] = bs[col]; bvv[ni] = bv[col]; wbv[ni] = wbeta[col];
  }
  float btsum[4];
  #pragma unroll
  for(int rr=0;rr<4;rr++){
    int row = l4*4 + rr;
    float bsum = 0.f;
    #pragma unroll
    for(int ni=0;ni<8;ni++){
      int col = w*128 + ni*16 + l15;
      float hp = acch[ni][rr] + bhv[ni];
      hpb[(size_t)(b0+row)*H_ + col] = hp + bvv[ni];
      float bt = fast_tanh((accs[ni][rr] + bsv[ni] + hp) * 0.70710678118654752f);
      bsum = fmaf(bt, wbv[ni], bsum);
    }
    btsum[rr] = bsum;
  }
  #pragma unroll
  for(int rr=0;rr<4;rr++){
    btsum[rr] += __shfl_xor(btsum[rr], 1);
    btsum[rr] += __shfl_xor(btsum[rr], 2);
    btsum[rr] += __shfl_xor(btsum[rr], 4);
    btsum[rr] += __shfl_xor(btsum[rr], 8);
    if(l15 == 0) zwp[w][l4*4+rr] = btsum[rr];
  }
  __syncthreads();
  if(tid < 16)
    beta[b0+tid] = zwp[0][tid] + zwp[1][tid] + zwp[2][tid] + zwp[3][tid] + bbeta_p[0];
}

// k_fused: one block/batch, N-split two-pass GEMM; distance-2 staging pipeline:
// chunk c+3 issued at iter c, written to LDS at iter c+2 (~2 iterations of MFMA
// cover the HBM latency). Disjoint chunk regions -> no WAR; 1 barrier/chunk.
__global__ __launch_bounds__(256, 2) void k_fused(
    const float* __restrict__ v, const ushort_* __restrict__ bpack,
    const float* __restrict__ hpb, const float* __restrict__ wz,
    const float* __restrict__ bz_p, const float* __restrict__ beta,
    const float* __restrict__ s, float* __restrict__ out)
{
  __shared__ __align__(16) ushort_ Av[49*512];   // 50KB bf16, swizzled granules
  __shared__ float zw[4][64];
  __shared__ float a_s[64];
  const int tid = threadIdx.x;
  const int w = tid >> 6, lane = tid & 63;
  const int l15 = lane & 15, l4 = lane >> 4;
  const int b = blockIdx.x;

  const f32x4* __restrict__ vsrc = (const f32x4*)(v + (size_t)b * T_ * H_);
  const bf16x8* __restrict__ bp = (const bf16x8*)bpack;
  const int bbase = w*256 + lane;            // pass p adds p*1024

  const int srow = tid >> 4, c4 = tid & 15;
  const int slot = ((c4 >> 1) ^ (srow & 7));
  const int wsub = ((c4 & 1) << 3);
  const bool r48 = (tid < 16);

#define VLOAD(N0,N1,N2,N3, CH) { \
    N0 = __builtin_nontemporal_load(vsrc + (srow     )*128 + (CH)*16 + c4); \
    N1 = __builtin_nontemporal_load(vsrc + (srow + 16)*128 + (CH)*16 + c4); \
    N2 = __builtin_nontemporal_load(vsrc + (srow + 32)*128 + (CH)*16 + c4); \
    if(r48) N3 = __builtin_nontemporal_load(vsrc + 48*128 + (CH)*16 + c4); }

#define SWRITE(N0,N1,N2,N3, CH) { \
    const int cb_ = (CH)*128; ushort4 u_; \
    u_.x=f2bf(N0[0]); u_.y=f2bf(N0[1]); u_.z=f2bf(N0[2]); u_.w=f2bf(N0[3]); \
    *(ushort4*)((char*)Av + (srow   )*1024 + cb_ + (slot<<4) + wsub) = u_; \
    u_.x=f2bf(N1[0]); u_.y=f2bf(N1[1]); u_.z=f2bf(N1[2]); u_.w=f2bf(N1[3]); \
    *(ushort4*)((char*)Av + (srow+16)*1024 + cb_ + (slot<<4) + wsub) = u_; \
    u_.x=f2bf(N2[0]); u_.y=f2bf(N2[1]); u_.z=f2bf(N2[2]); u_.w=f2bf(N2[3]); \
    *(ushort4*)((char*)Av + (srow+32)*1024 + cb_ + (slot<<4) + wsub) = u_; \
    if(r48){ \
      u_.x=f2bf(N3[0]); u_.y=f2bf(N3[1]); u_.z=f2bf(N3[2]); u_.w=f2bf(N3[3]); \
      *(ushort4*)((char*)Av + 48*1024 + cb_ + (slot<<4) + wsub) = u_; } }

#define AFRAG(af, KS) { \
    _Pragma("unroll") \
    for(int mi=0;mi<4;mi++){ \
      int row_ = (mi < 3) ? (mi*16 + l15) : 48; \
      int g_   = ((KS)*4 + l4) ^ (row_ & 7); \
      af[mi] = *(const bf16x8*)((const char*)Av + row_*1024 + (g_<<4)); } }

#define MFMA16(af, bfr) { \
    __builtin_amdgcn_s_setprio(1); \
    _Pragma("unroll") \
    for(int mi=0;mi<4;mi++) \
      _Pragma("unroll") \
      for(int ni=0;ni<4;ni++) \
        acc[mi][ni] = __builtin_amdgcn_mfma_f32_16x16x32_bf16(af[mi], bfr[ni], acc[mi][ni], 0,0,0); \
    __builtin_amdgcn_s_setprio(0); }

  f32x4 A0,A1,A2,A3, B0,B1,B2,B3;
  f32x4 acc[4][4];
  #pragma unroll
  for(int mi=0;mi<4;mi++)
    #pragma unroll
    for(int ni=0;ni<4;ni++) acc[mi][ni] = (f32x4){0.f,0.f,0.f,0.f};

  // ---- prologue: chunk 0 staged; chunks 1 (A_) and 2 (B_) in flight
  VLOAD(A0,A1,A2,A3, 0)
  SWRITE(A0,A1,A2,A3, 0)
  VLOAD(A0,A1,A2,A3, 1)
  VLOAD(B0,B1,B2,B3, 2)

  bf16x8 ba[4], bb[4], af[4];
  #pragma unroll
  for(int ni=0;ni<4;ni++) ba[ni] = bp[bbase + ni*64];      // kk=0, pass 0
  __syncthreads();

  // ---- pass 0: 8 chunks (2 K-steps each), cols 0..255; 2-unrolled rotation
#define BODY(C, W0,W1,W2,W3) { \
    _Pragma("unroll") \
    for(int ni=0;ni<4;ni++) bb[ni] = bp[(2*(C)+1)*2048 + bbase + ni*64]; \
    AFRAG(af, 2*(C)) \
    MFMA16(af, ba) \
    if((C) < 7){ SWRITE(W0,W1,W2,W3, (C)+1) } \
    if((C) < 5){ VLOAD(W0,W1,W2,W3, (C)+3) } \
    if((C) < 7){ \
      _Pragma("unroll") \
      for(int ni=0;ni<4;ni++) ba[ni] = bp[(2*(C)+2)*2048 + bbase + ni*64]; } \
    AFRAG(af, 2*(C)+1) \
    MFMA16(af, bb) \
    __syncthreads(); }

  #pragma unroll 1
  for(int cc=0; cc<4; cc++){
    const int c0 = 2*cc;
    BODY(c0,   A0,A1,A2,A3)
    BODY(c0+1, B0,B1,B2,B3)
  }

  // ---- pass-0 z-partials (cols w*64 .. w*64+63)
  {
    float wzv[4], hp0[4];
    #pragma unroll
    for(int ni=0;ni<4;ni++){
      int col = w*64 + ni*16 + l15;
      wzv[ni] = wz[col];
      hp0[ni] = hpb[(size_t)b*H_ + col];
    }
    float zp[16];
    #pragma unroll
    for(int mi=0;mi<4;mi++)
      #pragma unroll
      for(int r=0;r<4;r++){
        float az = 0.f;
        #pragma unroll
        for(int ni=0;ni<4;ni++)
          az = fmaf(fast_tanh(acc[mi][ni][r] + hp0[ni]), wzv[ni], az);
        zp[mi*4+r] = az;
      }
    #pragma unroll
    for(int i=0;i<16;i++){
      zp[i] += __shfl_xor(zp[i], 1);
      zp[i] += __shfl_xor(zp[i], 2);
      zp[i] += __shfl_xor(zp[i], 4);
      zp[i] += __shfl_xor(zp[i], 8);
    }
    if(l15 == 0){
      #pragma unroll
      for(int mi=0;mi<4;mi++)
        #pragma unroll
        for(int r=0;r<4;r++)
          zw[w][mi*16 + l4*4 + r] = zp[mi*4+r];
    }
  }

  // ---- pass 1: cols 256..511, straight from staged LDS
  #pragma unroll
  for(int mi=0;mi<4;mi++)
    #pragma unroll
    for(int ni=0;ni<4;ni++) acc[mi][ni] = (f32x4){0.f,0.f,0.f,0.f};

  #pragma unroll
  for(int ni=0;ni<4;ni++) ba[ni] = bp[1024 + bbase + ni*64];

  #pragma unroll 1
  for(int k2=0;k2<8;k2++){
    #pragma unroll
    for(int ni=0;ni<4;ni++) bb[ni] = bp[(2*k2+1)*2048 + 1024 + bbase + ni*64];
    AFRAG(af, 2*k2)
    MFMA16(af, ba)
    if(k2 < 7){
      #pragma unroll
      for(int ni=0;ni<4;ni++) ba[ni] = bp[(2*k2+2)*2048 + 1024 + bbase + ni*64];
    }
    AFRAG(af, 2*k2+1)
    MFMA16(af, bb)
  }

  // ---- pass-1 z-partials accumulated into zw
  {
    float wzv[4], hp0[4];
    #pragma unroll
    for(int ni=0;ni<4;ni++){
      int col = 256 + w*64 + ni*16 + l15;
      wzv[ni] = wz[col];
      hp0[ni] = hpb[(size_t)b*H_ + col];
    }
    float zp[16];
    #pragma unroll
    for(int mi=0;mi<4;mi++)
      #pragma unroll
      for(int r=0;r<4;r++){
        float az = 0.f;
        #pragma unroll
        for(int ni=0;ni<4;ni++)
          az = fmaf(fast_tanh(acc[mi][ni][r] + hp0[ni]), wzv[ni], az);
        zp[mi*4+r] = az;
      }
    #pragma unroll
    for(int i=0;i<16;i++){
      zp[i] += __shfl_xor(zp[i], 1);
      zp[i] += __shfl_xor(zp[i], 2);
      zp[i] += __shfl_xor(zp[i], 4);
      zp[i] += __shfl_xor(zp[i], 8);
    }
    if(l15 == 0){
      #pragma unroll
      for(int mi=0;mi<4;mi++)
        #pragma unroll
        for(int r=0;r<4;r++)
          zw[w][mi*16 + l4*4 + r] += zp[mi*4+r];
    }
  }
  __syncthreads();

  // ---- softmax over [z(49), beta] (wave 0)
  if(tid < 64){
    float zv;
    if(tid < T_)       zv = zw[0][tid] + zw[1][tid] + zw[2][tid] + zw[3][tid] + bz_p[0];
    else if(tid == T_) zv = beta[b];
    else               zv = -3.0e38f;
    float m = zv;
    #pragma unroll
    for(int off=32;off>=1;off>>=1) m = fmaxf(m, __shfl_xor(m, off));
    float e = (tid <= T_) ? __expf(zv - m) : 0.f;
    float ssum = e;
    #pragma unroll
    for(int off=32;off>=1;off>>=1) ssum += __shfl_xor(ssum, off);
    a_s[tid] = e * __builtin_amdgcn_rcpf(ssum);
  }
  __syncthreads();

  // ---- PV: c[n] = sum_t a[t]*v_bf16[t][n] + a[49]*s[b][n]; 2 cols/thread
  const int n0 = tid * 2;
  float ax = 0.f, ay = 0.f;
  #pragma unroll 7
  for(int t=0;t<T_;t++){
    float at = a_s[t];
    unsigned int u = *(const unsigned int*)((const char*)Av + t*1024
                       + ((((n0>>3) ^ (t&7)))<<4) + ((n0&7)<<1));
    float x = __uint_as_float((u & 0xFFFFu) << 16);
    float y = __uint_as_float(u & 0xFFFF0000u);
    ax = fmaf(at, x, ax);
    ay = fmaf(at, y, ay);
  }
  float a49 = a_s[T_];
  float2 sv = ((const float2*)(s + (size_t)b*H_))[tid];
  ax = fmaf(a49, sv.x, ax);
  ay = fmaf(a49, sv.y, ay);
  float2 res; res.x = ax; res.y = ay;
  ((float2*)(out + (size_t)b*H_))[tid] = res;
}

extern "C" void kernel_launch(void* const* d_in, const int* in_sizes, int n_in,
                              void* d_out, int out_size, void* d_ws, size_t ws_size,
                              hipStream_t stream)
{
  const float* v   = (const float*)d_in[0];
  const float* h   = (const float*)d_in[1];
  const float* s   = (const float*)d_in[2];
  const float* Wh  = (const float*)d_in[3];
  const float* bh  = (const float*)d_in[4];
  const float* Wv  = (const float*)d_in[5];
  const float* bv  = (const float*)d_in[6];
  const float* wz  = (const float*)d_in[7];
  const float* bz  = (const float*)d_in[8];
  const float* Ws  = (const float*)d_in[9];
  const float* bs  = (const float*)d_in[10];
  const float* wb  = (const float*)d_in[11];
  const float* bbet= (const float*)d_in[12];
  float* out = (float*)d_out;

  float* hpb  = (float*)d_ws;                      // B*H f32
  float* beta = hpb + (size_t)B_*H_;               // B f32
  ushort_* bpack = (ushort_*)(beta + B_);          // Wv frag-packed bf16
  ushort_* whp   = bpack + (size_t)H_*H_;          // Wh frag-packed
  ushort_* wsp   = whp   + (size_t)H_*H_;          // Ws frag-packed

  k_pack <<<128, 256, 0, stream>>>(Wv, bpack);
  k_pack <<<128, 256, 0, stream>>>(Wh, whp);
  k_pack <<<128, 256, 0, stream>>>(Ws, wsp);
  k_proj2<<<B_/16, 256, 0, stream>>>(h, s, whp, wsp, bh, bs, bv, wb, bbet, hpb, beta);
  k_fused<<<B_, 256, 0, stream>>>(v, bpack, hpb, wz, bz, beta, s, out);
}

// Round 8
// 218.006 us; speedup vs baseline: 1.0962x; 1.0962x over previous
//
#include <hip/hip_runtime.h>
#include <stdint.h>

#define B_ 4096
#define T_ 49
#define H_ 512
#define BT_ (B_*T_)
#define BB 16

typedef __bf16 bf16x8 __attribute__((ext_vector_type(8)));
typedef float  f32x4  __attribute__((ext_vector_type(4)));
typedef unsigned short ushort_;

__device__ __forceinline__ ushort_ f2bf(float f){
  unsigned int u = __float_as_uint(f);
  u += 0x7fffu + ((u >> 16) & 1u);           // RNE
  return (ushort_)(u >> 16);
}

__device__ __forceinline__ float fast_tanh(float x){
  float e = __expf(2.0f * x);
  return 1.0f - 2.0f * __builtin_amdgcn_rcpf(e + 1.0f);
}

// k_pack: W [K][N] f32 -> fragment-ordered bf16.
__global__ __launch_bounds__(256) void k_pack(const float* __restrict__ W,
                                              ushort_* __restrict__ pack){
  int idx = blockIdx.x * 256 + threadIdx.x;   // 0..32767
  int lane = idx & 63;
  int gt   = (idx >> 6) & 31;
  int kk   = idx >> 11;
  int col  = gt*16 + (lane & 15);
  int k0   = kk*32 + (lane >> 4)*8;
  ushort4 lo, hi;
  lo.x = f2bf(W[(k0+0)*H_ + col]);
  lo.y = f2bf(W[(k0+1)*H_ + col]);
  lo.z = f2bf(W[(k0+2)*H_ + col]);
  lo.w = f2bf(W[(k0+3)*H_ + col]);
  hi.x = f2bf(W[(k0+4)*H_ + col]);
  hi.y = f2bf(W[(k0+5)*H_ + col]);
  hi.z = f2bf(W[(k0+6)*H_ + col]);
  hi.w = f2bf(W[(k0+7)*H_ + col]);
  ushort4* dst = (ushort4*)pack;
  dst[idx*2]   = lo;
  dst[idx*2+1] = hi;
}

// k_proj2 (MFMA): 16 batches/block; h@W_h and s@W_s; epilogue hpb & beta.
__global__ __launch_bounds__(256) void k_proj2(
    const float* __restrict__ h, const float* __restrict__ s,
    const ushort_* __restrict__ whp, const ushort_* __restrict__ wsp,
    const float* __restrict__ bh, const float* __restrict__ bs,
    const float* __restrict__ bv, const float* __restrict__ wbeta,
    const float* __restrict__ bbeta_p,
    float* __restrict__ hpb, float* __restrict__ beta)
{
  __shared__ __align__(16) ushort_ hl[16*H_];   // 16KB, A-frag order
  __shared__ __align__(16) ushort_ sl[16*H_];
  __shared__ float zwp[4][16];
  const int tid = threadIdx.x;
  const int w = tid >> 6, lane = tid & 63;
  const int l15 = lane & 15, l4 = lane >> 4;
  const int b0 = blockIdx.x * 16;

  {
    const int r = tid >> 4;
    const float4* hsrc = (const float4*)(h + (size_t)(b0+r)*H_);
    const float4* ssrc = (const float4*)(s + (size_t)(b0+r)*H_);
    #pragma unroll
    for(int p=0;p<8;p++){
      int q  = (tid & 15) + p*16;         // float4 col
      int k0 = q*4;
      float4 fh = hsrc[q];
      float4 fs = ssrc[q];
      int idx = (k0>>5)*512 + ((((k0&31)>>3)<<4) + r)*8 + (k0&7);
      ushort4 uh; uh.x=f2bf(fh.x); uh.y=f2bf(fh.y); uh.z=f2bf(fh.z); uh.w=f2bf(fh.w);
      ushort4 us; us.x=f2bf(fs.x); us.y=f2bf(fs.y); us.z=f2bf(fs.z); us.w=f2bf(fs.w);
      *(ushort4*)&hl[idx] = uh;
      *(ushort4*)&sl[idx] = us;
    }
  }
  __syncthreads();

  const bf16x8* __restrict__ bph = (const bf16x8*)whp;
  const bf16x8* __restrict__ bps = (const bf16x8*)wsp;
  const int bbase = w*512 + lane;

  f32x4 acch[8], accs[8];
  #pragma unroll
  for(int ni=0;ni<8;ni++){ acch[ni]=(f32x4){0,0,0,0}; accs[ni]=(f32x4){0,0,0,0}; }

  #pragma unroll 2
  for(int kk=0;kk<16;kk++){
    bf16x8 ah = *(const bf16x8*)&hl[kk*512 + lane*8];
    bf16x8 as2 = *(const bf16x8*)&sl[kk*512 + lane*8];
    #pragma unroll
    for(int ni=0;ni<8;ni++){
      acch[ni] = __builtin_amdgcn_mfma_f32_16x16x32_bf16(ah,  bph[kk*2048 + bbase + ni*64], acch[ni], 0,0,0);
      accs[ni] = __builtin_amdgcn_mfma_f32_16x16x32_bf16(as2, bps[kk*2048 + bbase + ni*64], accs[ni], 0,0,0);
    }
  }

  float bhv[8], bsv[8], bvv[8], wbv[8];
  #pragma unroll
  for(int ni=0;ni<8;ni++){
    int col = w*128 + ni*16 + l15;
    bhv[ni] = bh[col]; bsv[ni] = bs[col]; bvv[ni] = bv[col]; wbv[ni] = wbeta[col];
  }
  float btsum[4];
  #pragma unroll
  for(int rr=0;rr<4;rr++){
    int row = l4*4 + rr;
    float bsum = 0.f;
    #pragma unroll
    for(int ni=0;ni<8;ni++){
      int col = w*128 + ni*16 + l15;
      float hp = acch[ni][rr] + bhv[ni];
      hpb[(size_t)(b0+row)*H_ + col] = hp + bvv[ni];
      float bt = fast_tanh((accs[ni][rr] + bsv[ni] + hp) * 0.70710678118654752f);
      bsum = fmaf(bt, wbv[ni], bsum);
    }
    btsum[rr] = bsum;
  }
  #pragma unroll
  for(int rr=0;rr<4;rr++){
    btsum[rr] += __shfl_xor(btsum[rr], 1);
    btsum[rr] += __shfl_xor(btsum[rr], 2);
    btsum[rr] += __shfl_xor(btsum[rr], 4);
    btsum[rr] += __shfl_xor(btsum[rr], 8);
    if(l15 == 0) zwp[w][l4*4+rr] = btsum[rr];
  }
  __syncthreads();
  if(tid < 16)
    beta[b0+tid] = zwp[0][tid] + zwp[1][tid] + zwp[2][tid] + zwp[3][tid] + bbeta_p[0];
}

// k_fused: one block/batch. Convoy-free structure: (1) stage whole v[b] tile
// (bf16, swizzled) with a dbuf reg rotation, NO barriers inside; (2) ONE
// __syncthreads; (3) pure GEMM (2 N-passes x 16 K-steps) with zero barriers --
// only vmcnt stream is the rolling B-frag prefetch, waves drift freely so
// HBM/L2/MFMA pipes overlap across the 12 waves/CU.
__global__ __launch_bounds__(256, 3) void k_fused(
    const float* __restrict__ v, const ushort_* __restrict__ bpack,
    const float* __restrict__ hpb, const float* __restrict__ wz,
    const float* __restrict__ bz_p, const float* __restrict__ beta,
    const float* __restrict__ s, float* __restrict__ out)
{
  __shared__ __align__(16) ushort_ Av[49*512];   // 50KB bf16, swizzled granules
  __shared__ float zw[4][64];
  __shared__ float a_s[64];
  const int tid = threadIdx.x;
  const int w = tid >> 6, lane = tid & 63;
  const int l15 = lane & 15, l4 = lane >> 4;
  const int b = blockIdx.x;

  const f32x4* __restrict__ vsrc = (const f32x4*)(v + (size_t)b * T_ * H_);
  const bf16x8* __restrict__ bp = (const bf16x8*)bpack;
  const int bbase = w*256 + lane;            // pass p adds p*1024

  const int srow = tid >> 4, c4 = tid & 15;
  const int slot = ((c4 >> 1) ^ (srow & 7));
  const int wsub = ((c4 & 1) << 3);
  const bool r48 = (tid < 16);

#define VLOAD(N0,N1,N2,N3, CH) { \
    N0 = __builtin_nontemporal_load(vsrc + (srow     )*128 + (CH)*16 + c4); \
    N1 = __builtin_nontemporal_load(vsrc + (srow + 16)*128 + (CH)*16 + c4); \
    N2 = __builtin_nontemporal_load(vsrc + (srow + 32)*128 + (CH)*16 + c4); \
    if(r48) N3 = __builtin_nontemporal_load(vsrc + 48*128 + (CH)*16 + c4); }

#define SWRITE(N0,N1,N2,N3, CH) { \
    const int cb_ = (CH)*128; ushort4 u_; \
    u_.x=f2bf(N0[0]); u_.y=f2bf(N0[1]); u_.z=f2bf(N0[2]); u_.w=f2bf(N0[3]); \
    *(ushort4*)((char*)Av + (srow   )*1024 + cb_ + (slot<<4) + wsub) = u_; \
    u_.x=f2bf(N1[0]); u_.y=f2bf(N1[1]); u_.z=f2bf(N1[2]); u_.w=f2bf(N1[3]); \
    *(ushort4*)((char*)Av + (srow+16)*1024 + cb_ + (slot<<4) + wsub) = u_; \
    u_.x=f2bf(N2[0]); u_.y=f2bf(N2[1]); u_.z=f2bf(N2[2]); u_.w=f2bf(N2[3]); \
    *(ushort4*)((char*)Av + (srow+32)*1024 + cb_ + (slot<<4) + wsub) = u_; \
    if(r48){ \
      u_.x=f2bf(N3[0]); u_.y=f2bf(N3[1]); u_.z=f2bf(N3[2]); u_.w=f2bf(N3[3]); \
      *(ushort4*)((char*)Av + 48*1024 + cb_ + (slot<<4) + wsub) = u_; } }

#define AFRAG(af, KS) { \
    _Pragma("unroll") \
    for(int mi=0;mi<4;mi++){ \
      int row_ = (mi < 3) ? (mi*16 + l15) : 48; \
      int g_   = ((KS)*4 + l4) ^ (row_ & 7); \
      af[mi] = *(const bf16x8*)((const char*)Av + row_*1024 + (g_<<4)); } }

#define MFMA16(af, bfr) { \
    __builtin_amdgcn_s_setprio(1); \
    _Pragma("unroll") \
    for(int mi=0;mi<4;mi++) \
      _Pragma("unroll") \
      for(int ni=0;ni<4;ni++) \
        acc[mi][ni] = __builtin_amdgcn_mfma_f32_16x16x32_bf16(af[mi], bfr[ni], acc[mi][ni], 0,0,0); \
    __builtin_amdgcn_s_setprio(0); }

  // ---- stage: whole 49x512 tile, dbuf rotation, no barriers (waves free-run)
  {
    f32x4 A0,A1,A2,A3, B0,B1,B2,B3;
    VLOAD(A0,A1,A2,A3, 0)
    #pragma unroll
    for(int cc=0; cc<4; cc++){
      VLOAD(B0,B1,B2,B3, 2*cc+1)
      SWRITE(A0,A1,A2,A3, 2*cc)            // waits chunk-2cc loads only (older)
      if(cc < 3) VLOAD(A0,A1,A2,A3, 2*cc+2)
      SWRITE(B0,B1,B2,B3, 2*cc+1)
    }
  }

  f32x4 acc[4][4];
  #pragma unroll
  for(int mi=0;mi<4;mi++)
    #pragma unroll
    for(int ni=0;ni<4;ni++) acc[mi][ni] = (f32x4){0.f,0.f,0.f,0.f};

  bf16x8 ba[4], bb[4], af[4];
  #pragma unroll
  for(int ni=0;ni<4;ni++) ba[ni] = bp[bbase + ni*64];      // kk=0, pass 0
  __syncthreads();                           // the ONLY staging barrier

  // ---- pass 0: cols w*64 .. w*64+63 (of 0..255 quadrant layout), 16 K-steps
  #pragma unroll 1
  for(int kk=0; kk<16; kk+=2){
    #pragma unroll
    for(int ni=0;ni<4;ni++) bb[ni] = bp[(kk+1)*2048 + bbase + ni*64];
    AFRAG(af, kk)
    MFMA16(af, ba)
    if(kk < 14){
      #pragma unroll
      for(int ni=0;ni<4;ni++) ba[ni] = bp[(kk+2)*2048 + bbase + ni*64];
    }
    AFRAG(af, kk+1)
    MFMA16(af, bb)
  }

  // ---- pass-0 z-partials (cols w*64 .. w*64+63)
  {
    float wzv[4], hp0[4];
    #pragma unroll
    for(int ni=0;ni<4;ni++){
      int col = w*64 + ni*16 + l15;
      wzv[ni] = wz[col];
      hp0[ni] = hpb[(size_t)b*H_ + col];
    }
    float zp[16];
    #pragma unroll
    for(int mi=0;mi<4;mi++)
      #pragma unroll
      for(int r=0;r<4;r++){
        float az = 0.f;
        #pragma unroll
        for(int ni=0;ni<4;ni++)
          az = fmaf(fast_tanh(acc[mi][ni][r] + hp0[ni]), wzv[ni], az);
        zp[mi*4+r] = az;
      }
    #pragma unroll
    for(int i=0;i<16;i++){
      zp[i] += __shfl_xor(zp[i], 1);
      zp[i] += __shfl_xor(zp[i], 2);
      zp[i] += __shfl_xor(zp[i], 4);
      zp[i] += __shfl_xor(zp[i], 8);
    }
    if(l15 == 0){
      #pragma unroll
      for(int mi=0;mi<4;mi++)
        #pragma unroll
        for(int r=0;r<4;r++)
          zw[w][mi*16 + l4*4 + r] = zp[mi*4+r];
    }
  }

  // ---- pass 1: cols 256..511, same staged LDS, no barriers
  #pragma unroll
  for(int mi=0;mi<4;mi++)
    #pragma unroll
    for(int ni=0;ni<4;ni++) acc[mi][ni] = (f32x4){0.f,0.f,0.f,0.f};

  #pragma unroll
  for(int ni=0;ni<4;ni++) ba[ni] = bp[1024 + bbase + ni*64];

  #pragma unroll 1
  for(int kk=0; kk<16; kk+=2){
    #pragma unroll
    for(int ni=0;ni<4;ni++) bb[ni] = bp[(kk+1)*2048 + 1024 + bbase + ni*64];
    AFRAG(af, kk)
    MFMA16(af, ba)
    if(kk < 14){
      #pragma unroll
      for(int ni=0;ni<4;ni++) ba[ni] = bp[(kk+2)*2048 + 1024 + bbase + ni*64];
    }
    AFRAG(af, kk+1)
    MFMA16(af, bb)
  }

  // ---- pass-1 z-partials accumulated into zw
  {
    float wzv[4], hp0[4];
    #pragma unroll
    for(int ni=0;ni<4;ni++){
      int col = 256 + w*64 + ni*16 + l15;
      wzv[ni] = wz[col];
      hp0[ni] = hpb[(size_t)b*H_ + col];
    }
    float zp[16];
    #pragma unroll
    for(int mi=0;mi<4;mi++)
      #pragma unroll
      for(int r=0;r<4;r++){
        float az = 0.f;
        #pragma unroll
        for(int ni=0;ni<4;ni++)
          az = fmaf(fast_tanh(acc[mi][ni][r] + hp0[ni]), wzv[ni], az);
        zp[mi*4+r] = az;
      }
    #pragma unroll
    for(int i=0;i<16;i++){
      zp[i] += __shfl_xor(zp[i], 1);
      zp[i] += __shfl_xor(zp[i], 2);
      zp[i] += __shfl_xor(zp[i], 4);
      zp[i] += __shfl_xor(zp[i], 8);
    }
    if(l15 == 0){
      #pragma unroll
      for(int mi=0;mi<4;mi++)
        #pragma unroll
        for(int r=0;r<4;r++)
          zw[w][mi*16 + l4*4 + r] += zp[mi*4+r];
    }
  }
  __syncthreads();

  // ---- softmax over [z(49), beta] (wave 0)
  if(tid < 64){
    float zv;
    if(tid < T_)       zv = zw[0][tid] + zw[1][tid] + zw[2][tid] + zw[3][tid] + bz_p[0];
    else if(tid == T_) zv = beta[b];
    else               zv = -3.0e38f;
    float m = zv;
    #pragma unroll
    for(int off=32;off>=1;off>>=1) m = fmaxf(m, __shfl_xor(m, off));
    float e = (tid <= T_) ? __expf(zv - m) : 0.f;
    float ssum = e;
    #pragma unroll
    for(int off=32;off>=1;off>>=1) ssum += __shfl_xor(ssum, off);
    a_s[tid] = e * __builtin_amdgcn_rcpf(ssum);
  }
  __syncthreads();

  // ---- PV: c[n] = sum_t a[t]*v_bf16[t][n] + a[49]*s[b][n]; 2 cols/thread
  const int n0 = tid * 2;
  float ax = 0.f, ay = 0.f;
  #pragma unroll 7
  for(int t=0;t<T_;t++){
    float at = a_s[t];
    unsigned int u = *(const unsigned int*)((const char*)Av + t*1024
                       + ((((n0>>3) ^ (t&7)))<<4) + ((n0&7)<<1));
    float x = __uint_as_float((u & 0xFFFFu) << 16);
    float y = __uint_as_float(u & 0xFFFF0000u);
    ax = fmaf(at, x, ax);
    ay = fmaf(at, y, ay);
  }
  float a49 = a_s[T_];
  float2 sv = ((const float2*)(s + (size_t)b*H_))[tid];
  ax = fmaf(a49, sv.x, ax);
  ay = fmaf(a49, sv.y, ay);
  float2 res; res.x = ax; res.y = ay;
  ((float2*)(out + (size_t)b*H_))[tid] = res;
}

extern "C" void kernel_launch(void* const* d_in, const int* in_sizes, int n_in,
                              void* d_out, int out_size, void* d_ws, size_t ws_size,
                              hipStream_t stream)
{
  const float* v   = (const float*)d_in[0];
  const float* h   = (const float*)d_in[1];
  const float* s   = (const float*)d_in[2];
  const float* Wh  = (const float*)d_in[3];
  const float* bh  = (const float*)d_in[4];
  const float* Wv  = (const float*)d_in[5];
  const float* bv  = (const float*)d_in[6];
  const float* wz  = (const float*)d_in[7];
  const float* bz  = (const float*)d_in[8];
  const float* Ws  = (const float*)d_in[9];
  const float* bs  = (const float*)d_in[10];
  const float* wb  = (const float*)d_in[11];
  const float* bbet= (const float*)d_in[12];
  float* out = (float*)d_out;

  float* hpb  = (float*)d_ws;                      // B*H f32
  float* beta = hpb + (size_t)B_*H_;               // B f32
  ushort_* bpack = (ushort_*)(beta + B_);          // Wv frag-packed bf16
  ushort_* whp   = bpack + (size_t)H_*H_;          // Wh frag-packed
  ushort_* wsp   = whp   + (size_t)H_*H_;          // Ws frag-packed

  k_pack <<<128, 256, 0, stream>>>(Wv, bpack);
  k_pack <<<128, 256, 0, stream>>>(Wh, whp);
  k_pack <<<128, 256, 0, stream>>>(Ws, wsp);
  k_proj2<<<B_/16, 256, 0, stream>>>(h, s, whp, wsp, bh, bs, bv, wb, bbet, hpb, beta);
  k_fused<<<B_, 256, 0, stream>>>(v, bpack, hpb, wz, bz, beta, s, out);
}